// Round 5
// baseline (819.434 us; speedup 1.0000x reference)
//
#include <hip/hip_runtime.h>
#include <hip/hip_bf16.h>

#define N_NODES 100000
#define N_EDGES 1600000
#define D       64
#define N_RELS  200
#define LEAKY   0.01f
#define NB      ((N_NODES + 255) / 256)   // 391 scan blocks

typedef __hip_bfloat16 bf16;

__device__ __forceinline__ float b2f(bf16 x) { return __bfloat162float(x); }

// dtype-dispatching float load: bf==1 -> storage is bf16, else f32 (probe says f32 here)
__device__ __forceinline__ float ldf(const void* p, long i, int bf) {
    return bf ? __bfloat162float(((const bf16*)p)[i]) : ((const float*)p)[i];
}
__device__ __forceinline__ int probe_bf(const void* delta) {
    return ((const unsigned short*)delta)[0] == 0x3F80 ? 1 : 0;
}

__global__ __launch_bounds__(256) void k_init(int* __restrict__ cnt) {
    int i = blockIdx.x * blockDim.x + threadIdx.x;
    if (i < N_NODES) cnt[i] = 0;
}

// hW(bf16) = h @ Wn[:D], s_src = h @ a1, s_dst = h @ a2  (wave per node)
__global__ __launch_bounds__(256) void k_node_proj(const void* __restrict__ h,
                                                   const void* __restrict__ wn,
                                                   const void* __restrict__ attn,
                                                   const void* __restrict__ delta,
                                                   bf16* __restrict__ hWb,
                                                   float* __restrict__ s_src,
                                                   float* __restrict__ s_dst) {
    const int bf = probe_bf(delta);
    __shared__ float W1[D * D];
    __shared__ float A1[D], A2[D];
    for (int t = threadIdx.x; t < D * D; t += 256) W1[t] = ldf(wn, t, bf);
    for (int t = threadIdx.x; t < D; t += 256) { A1[t] = ldf(attn, t, bf); A2[t] = ldf(attn, D + t, bf); }
    __syncthreads();
    const int wave = threadIdx.x >> 6;
    const int lane = threadIdx.x & 63;
    const int wstride = gridDim.x * 4;
    for (int i = blockIdx.x * 4 + wave; i < N_NODES; i += wstride) {
        float hv = ldf(h, (long)i * D + lane, bf);
        float p1 = hv * A1[lane];
        float p2 = hv * A2[lane];
        #pragma unroll
        for (int off = 32; off; off >>= 1) { p1 += __shfl_xor(p1, off); p2 += __shfl_xor(p2, off); }
        if (lane == 0) { s_src[i] = p1; s_dst[i] = p2; }
        float acc = 0.f;
        #pragma unroll
        for (int k = 0; k < D; k++) {
            float hk = __shfl(hv, k);
            acc += hk * W1[k * D + lane];
        }
        hWb[i * D + lane] = __float2bfloat16(acc);
    }
}

// relW(f32) = rel_emb @ Wn[D:], s_rel = rel_emb @ a3  (wave per relation)
__global__ __launch_bounds__(256) void k_rel_proj(const void* __restrict__ rel_emb,
                                                  const void* __restrict__ wn,
                                                  const void* __restrict__ attn,
                                                  const void* __restrict__ delta,
                                                  float* __restrict__ relW,
                                                  float* __restrict__ s_rel) {
    const int bf = probe_bf(delta);
    __shared__ float W2[D * D];
    __shared__ float A3[D];
    for (int t = threadIdx.x; t < D * D; t += 256) W2[t] = ldf(wn, D * D + t, bf);
    for (int t = threadIdx.x; t < D; t += 256) A3[t] = ldf(attn, 2 * D + t, bf);
    __syncthreads();
    const int wave = threadIdx.x >> 6;
    const int lane = threadIdx.x & 63;
    const int wstride = gridDim.x * 4;
    for (int i = blockIdx.x * 4 + wave; i < N_RELS; i += wstride) {
        float hv = ldf(rel_emb, (long)i * D + lane, bf);
        float p3 = hv * A3[lane];
        #pragma unroll
        for (int off = 32; off; off >>= 1) p3 += __shfl_xor(p3, off);
        if (lane == 0) s_rel[i] = p3;
        float acc = 0.f;
        #pragma unroll
        for (int k = 0; k < D; k++) {
            float hk = __shfl(hv, k);
            acc += hk * W2[k * D + lane];
        }
        relW[i * D + lane] = acc;
    }
}

// histogram of dst
__global__ __launch_bounds__(256) void k_hist(const int* __restrict__ dst, int* __restrict__ cnt) {
    int t = blockIdx.x * blockDim.x + threadIdx.x;
    if (t < N_EDGES) atomicAdd(&cnt[dst[t]], 1);
}

// per-block sums of cnt
__global__ __launch_bounds__(256) void k_scan1(const int* __restrict__ cnt, int* __restrict__ blocksum) {
    __shared__ int s[256];
    int i = blockIdx.x * 256 + threadIdx.x;
    s[threadIdx.x] = (i < N_NODES) ? cnt[i] : 0;
    __syncthreads();
    for (int off = 128; off; off >>= 1) {
        if (threadIdx.x < off) s[threadIdx.x] += s[threadIdx.x + off];
        __syncthreads();
    }
    if (threadIdx.x == 0) blocksum[blockIdx.x] = s[0];
}

// exclusive scan of blocksums (one block); also writes rowptr[N_NODES]
__global__ __launch_bounds__(256) void k_scan2(const int* __restrict__ blocksum,
                                               int* __restrict__ blockbase,
                                               int* __restrict__ rowptr) {
    __shared__ int s[NB];
    for (int t = threadIdx.x; t < NB; t += 256) s[t] = blocksum[t];
    __syncthreads();
    if (threadIdx.x == 0) {
        int run = 0;
        for (int b = 0; b < NB; b++) { int v = s[b]; s[b] = run; run += v; }
        rowptr[N_NODES] = run;
    }
    __syncthreads();
    for (int t = threadIdx.x; t < NB; t += 256) blockbase[t] = s[t];
}

// per-block exclusive scan + base -> rowptr, cursor
__global__ __launch_bounds__(256) void k_scan3(const int* __restrict__ cnt,
                                               const int* __restrict__ blockbase,
                                               int* __restrict__ rowptr,
                                               int* __restrict__ cursor) {
    __shared__ int s[256];
    int i = blockIdx.x * 256 + threadIdx.x;
    int v = (i < N_NODES) ? cnt[i] : 0;
    s[threadIdx.x] = v;
    __syncthreads();
    for (int off = 1; off < 256; off <<= 1) {
        int t = (threadIdx.x >= off) ? s[threadIdx.x - off] : 0;
        __syncthreads();
        s[threadIdx.x] += t;
        __syncthreads();
    }
    if (i < N_NODES) {
        int rp = blockbase[blockIdx.x] + s[threadIdx.x] - v;   // exclusive
        rowptr[i] = rp;
        cursor[i] = rp;
    }
}

// per-edge score + scatter {score,src,etype} into dst-sorted slots
__global__ __launch_bounds__(256) void k_edge_score(const float* __restrict__ s_src,
                                                    const float* __restrict__ s_dst,
                                                    const float* __restrict__ s_rel,
                                                    const void* __restrict__ etime,
                                                    const void* __restrict__ delta,
                                                    const int* __restrict__ src,
                                                    const int* __restrict__ dst,
                                                    const int* __restrict__ etype,
                                                    int* __restrict__ cursor,
                                                    int4* __restrict__ sorted) {
    const int bf = probe_bf(delta);
    int t = blockIdx.x * blockDim.x + threadIdx.x;
    if (t >= N_EDGES) return;
    float df = ldf(delta, 0, bf);
    int s = src[t], d = dst[t], r = etype[t];
    float sc = s_src[s] + s_dst[d] + s_rel[r];
    float e = sc > 0.f ? sc : LEAKY * sc;
    float score = (-ldf(etime, t, bf) * df) * e;
    int pos = atomicAdd(&cursor[d], 1);
    int4 rec;
    rec.x = __float_as_int(score);
    rec.y = s;
    rec.z = r;
    rec.w = 0;
    sorted[pos] = rec;
}

// wave per node: segment softmax + weighted message gather + fused epilogue
__global__ __launch_bounds__(256) void k_aggregate(const int* __restrict__ rowptr,
                                                   const int4* __restrict__ sorted,
                                                   const bf16* __restrict__ hWb,
                                                   const float* __restrict__ relW,
                                                   const void* __restrict__ h,
                                                   const void* __restrict__ loopW,
                                                   const void* __restrict__ evolveW,
                                                   const void* __restrict__ delta,
                                                   float* __restrict__ out) {
    const int bf = probe_bf(delta);
    __shared__ float WL[D * D];
    __shared__ float WE[D * D];
    for (int t = threadIdx.x; t < D * D; t += 256) { WL[t] = ldf(loopW, t, bf); WE[t] = ldf(evolveW, t, bf); }
    __syncthreads();
    const int wave = threadIdx.x >> 6;
    const int lane = threadIdx.x & 63;
    const int wstride = gridDim.x * 4;
    for (int i = blockIdx.x * 4 + wave; i < N_NODES; i += wstride) {
        int s0 = rowptr[i], e1 = rowptr[i + 1];
        float hv = ldf(h, (long)i * D + lane, bf);
        float acc;
        const float* W;
        if (e1 > s0) {
            // phase 1: segment max + exp-sum (lanes parallel over edges, coalesced)
            float lm = -3.4e38f;
            for (int j = s0 + lane; j < e1; j += 64)
                lm = fmaxf(lm, __int_as_float(sorted[j].x));
            #pragma unroll
            for (int off = 32; off; off >>= 1) lm = fmaxf(lm, __shfl_xor(lm, off));
            float ls = 0.f;
            for (int j = s0 + lane; j < e1; j += 64)
                ls += __expf(__int_as_float(sorted[j].x) - lm);
            #pragma unroll
            for (int off = 32; off; off >>= 1) ls += __shfl_xor(ls, off);
            float invden = 1.f / ls;   // ls >= 1 (argmax edge contributes 1)
            // phase 2: weighted message accumulate (broadcast rec, coalesced row gathers)
            acc = 0.f;
            for (int e = s0; e < e1; ++e) {
                int4 rec = sorted[e];
                float w = __expf(__int_as_float(rec.x) - lm) * invden;
                float msg = b2f(hWb[(long)rec.y * D + lane]) + relW[rec.z * D + lane];
                acc += w * msg;
            }
            W = WL;
        } else {
            acc = hv;
            W = WE;
        }
        // fused epilogue: acc += h[i] @ W
        #pragma unroll
        for (int k = 0; k < D; k++) {
            float hk = __shfl(hv, k);
            acc += hk * W[k * D + lane];
        }
        out[(long)i * D + lane] = acc;
    }
}

// safe diagnostic fallback
__global__ __launch_bounds__(256) void k_fallback(float* __restrict__ out) {
    int t = blockIdx.x * blockDim.x + threadIdx.x;
    if (t < N_NODES * D) out[t] = 0.f;
}

extern "C" void kernel_launch(void* const* d_in, const int* in_sizes, int n_in,
                              void* d_out, int out_size, void* d_ws, size_t ws_size,
                              hipStream_t stream) {
    const void* h       = d_in[0];
    const void* rel_emb = d_in[1];
    const void* wn      = d_in[2];
    const void* attn    = d_in[3];
    const void* delta   = d_in[4];
    const void* loopW   = d_in[5];
    const void* evolveW = d_in[6];
    const void* etime   = d_in[7];
    const int*  src     = (const int*)d_in[8];
    const int*  dst     = (const int*)d_in[9];
    const int*  etype   = (const int*)d_in[10];
    float* out = (float*)d_out;

    char* ws = (char*)d_ws;
    size_t off = 0;
    auto alloc = [&](size_t bytes) -> void* {
        off = (off + 255) & ~(size_t)255;
        void* p = ws + off;
        off += bytes;
        return p;
    };
    int4*  sorted  = (int4*) alloc((size_t)N_EDGES * 16);      // 25.6 MB
    bf16*  hWb     = (bf16*) alloc((size_t)N_NODES * D * 2);   // 12.8 MB
    float* relW    = (float*)alloc((size_t)N_RELS * D * 4);    // 51.2 KB
    float* s_src   = (float*)alloc((size_t)N_NODES * 4);       //  0.4 MB
    float* s_dst   = (float*)alloc((size_t)N_NODES * 4);       //  0.4 MB
    float* s_rel   = (float*)alloc((size_t)N_RELS * 4);        //  0.8 KB
    int*   cnt     = (int*)  alloc((size_t)N_NODES * 4);       //  0.4 MB
    int*   rowptr  = (int*)  alloc((size_t)(N_NODES + 1) * 4); //  0.4 MB
    int*   cursor  = (int*)  alloc((size_t)N_NODES * 4);       //  0.4 MB
    int*   blocksum  = (int*)alloc((size_t)NB * 4);
    int*   blockbase = (int*)alloc((size_t)NB * 4);

    if (ws_size < off) {
        k_fallback<<<(N_NODES * D + 255) / 256, 256, 0, stream>>>(out);
        return;
    }

    k_init<<<(N_NODES + 255) / 256, 256, 0, stream>>>(cnt);
    k_node_proj<<<1024, 256, 0, stream>>>(h, wn, attn, delta, hWb, s_src, s_dst);
    k_rel_proj<<<50, 256, 0, stream>>>(rel_emb, wn, attn, delta, relW, s_rel);
    k_hist<<<(N_EDGES + 255) / 256, 256, 0, stream>>>(dst, cnt);
    k_scan1<<<NB, 256, 0, stream>>>(cnt, blocksum);
    k_scan2<<<1, 256, 0, stream>>>(blocksum, blockbase, rowptr);
    k_scan3<<<NB, 256, 0, stream>>>(cnt, blockbase, rowptr, cursor);
    k_edge_score<<<(N_EDGES + 255) / 256, 256, 0, stream>>>(s_src, s_dst, s_rel, etime, delta,
                                                            src, dst, etype, cursor, sorted);
    k_aggregate<<<25000, 256, 0, stream>>>(rowptr, sorted, hWb, relW, h, loopW, evolveW, delta, out);
    (void)rel_emb;
}

// Round 6
// 402.255 us; speedup vs baseline: 2.0371x; 2.0371x over previous
//
#include <hip/hip_runtime.h>
#include <hip/hip_bf16.h>

#define N_NODES 100000
#define N_EDGES 1600000
#define D       64
#define N_RELS  200
#define LEAKY   0.01f
#define NB      ((N_NODES + 255) / 256)   // 391 scan blocks

typedef __hip_bfloat16 bf16;

__device__ __forceinline__ float b2f(bf16 x) { return __bfloat162float(x); }

// dtype-dispatching float load: bf==1 -> storage is bf16, else f32 (probe says f32 here)
__device__ __forceinline__ float ldf(const void* p, long i, int bf) {
    return bf ? __bfloat162float(((const bf16*)p)[i]) : ((const float*)p)[i];
}
__device__ __forceinline__ int probe_bf(const void* delta) {
    return ((const unsigned short*)delta)[0] == 0x3F80 ? 1 : 0;
}

// uniform-index lane broadcast via v_readlane (result lands in SGPR)
__device__ __forceinline__ int rl_i(int v, int l) {
    return __builtin_amdgcn_readlane(v, l);
}
__device__ __forceinline__ float rl_f(float v, int l) {
    return __int_as_float(__builtin_amdgcn_readlane(__float_as_int(v), l));
}

__global__ __launch_bounds__(256) void k_init(int* __restrict__ cnt) {
    int i = blockIdx.x * blockDim.x + threadIdx.x;
    if (i < N_NODES) cnt[i] = 0;
}

// hW(bf16) = h @ Wn[:D], s_src = h @ a1, s_dst = h @ a2  (wave per node, 8 waves/block)
__global__ __launch_bounds__(512, 4) void k_node_proj(const void* __restrict__ h,
                                                      const void* __restrict__ wn,
                                                      const void* __restrict__ attn,
                                                      const void* __restrict__ delta,
                                                      bf16* __restrict__ hWb,
                                                      float* __restrict__ s_src,
                                                      float* __restrict__ s_dst) {
    const int bf = probe_bf(delta);
    __shared__ float W1[D * D];
    __shared__ float A1[D], A2[D];
    for (int t = threadIdx.x; t < D * D; t += 512) W1[t] = ldf(wn, t, bf);
    for (int t = threadIdx.x; t < D; t += 512) { A1[t] = ldf(attn, t, bf); A2[t] = ldf(attn, D + t, bf); }
    __syncthreads();
    const int wave = threadIdx.x >> 6;
    const int lane = threadIdx.x & 63;
    const int wstride = gridDim.x * 8;
    for (int i = blockIdx.x * 8 + wave; i < N_NODES; i += wstride) {
        float hv = ldf(h, (long)i * D + lane, bf);
        float p1 = hv * A1[lane];
        float p2 = hv * A2[lane];
        #pragma unroll
        for (int off = 32; off; off >>= 1) { p1 += __shfl_xor(p1, off); p2 += __shfl_xor(p2, off); }
        if (lane == 0) { s_src[i] = p1; s_dst[i] = p2; }
        float acc = 0.f;
        #pragma unroll
        for (int k = 0; k < D; k++) {
            acc += rl_f(hv, k) * W1[k * D + lane];
        }
        hWb[i * D + lane] = __float2bfloat16(acc);
    }
}

// relW(f32) = rel_emb @ Wn[D:], s_rel = rel_emb @ a3  (wave per relation)
__global__ __launch_bounds__(256) void k_rel_proj(const void* __restrict__ rel_emb,
                                                  const void* __restrict__ wn,
                                                  const void* __restrict__ attn,
                                                  const void* __restrict__ delta,
                                                  float* __restrict__ relW,
                                                  float* __restrict__ s_rel) {
    const int bf = probe_bf(delta);
    __shared__ float W2[D * D];
    __shared__ float A3[D];
    for (int t = threadIdx.x; t < D * D; t += 256) W2[t] = ldf(wn, D * D + t, bf);
    for (int t = threadIdx.x; t < D; t += 256) A3[t] = ldf(attn, 2 * D + t, bf);
    __syncthreads();
    const int wave = threadIdx.x >> 6;
    const int lane = threadIdx.x & 63;
    const int wstride = gridDim.x * 4;
    for (int i = blockIdx.x * 4 + wave; i < N_RELS; i += wstride) {
        float hv = ldf(rel_emb, (long)i * D + lane, bf);
        float p3 = hv * A3[lane];
        #pragma unroll
        for (int off = 32; off; off >>= 1) p3 += __shfl_xor(p3, off);
        if (lane == 0) s_rel[i] = p3;
        float acc = 0.f;
        #pragma unroll
        for (int k = 0; k < D; k++) {
            acc += rl_f(hv, k) * W2[k * D + lane];
        }
        relW[i * D + lane] = acc;
    }
}

// histogram of dst
__global__ __launch_bounds__(256) void k_hist(const int* __restrict__ dst, int* __restrict__ cnt) {
    int t = blockIdx.x * blockDim.x + threadIdx.x;
    if (t < N_EDGES) atomicAdd(&cnt[dst[t]], 1);
}

// per-block sums of cnt
__global__ __launch_bounds__(256) void k_scan1(const int* __restrict__ cnt, int* __restrict__ blocksum) {
    __shared__ int s[256];
    int i = blockIdx.x * 256 + threadIdx.x;
    s[threadIdx.x] = (i < N_NODES) ? cnt[i] : 0;
    __syncthreads();
    for (int off = 128; off; off >>= 1) {
        if (threadIdx.x < off) s[threadIdx.x] += s[threadIdx.x + off];
        __syncthreads();
    }
    if (threadIdx.x == 0) blocksum[blockIdx.x] = s[0];
}

// exclusive scan of blocksums (one block); also writes rowptr[N_NODES]
__global__ __launch_bounds__(256) void k_scan2(const int* __restrict__ blocksum,
                                               int* __restrict__ blockbase,
                                               int* __restrict__ rowptr) {
    __shared__ int s[NB];
    for (int t = threadIdx.x; t < NB; t += 256) s[t] = blocksum[t];
    __syncthreads();
    if (threadIdx.x == 0) {
        int run = 0;
        for (int b = 0; b < NB; b++) { int v = s[b]; s[b] = run; run += v; }
        rowptr[N_NODES] = run;
    }
    __syncthreads();
    for (int t = threadIdx.x; t < NB; t += 256) blockbase[t] = s[t];
}

// per-block exclusive scan + base -> rowptr, cursor
__global__ __launch_bounds__(256) void k_scan3(const int* __restrict__ cnt,
                                               const int* __restrict__ blockbase,
                                               int* __restrict__ rowptr,
                                               int* __restrict__ cursor) {
    __shared__ int s[256];
    int i = blockIdx.x * 256 + threadIdx.x;
    int v = (i < N_NODES) ? cnt[i] : 0;
    s[threadIdx.x] = v;
    __syncthreads();
    for (int off = 1; off < 256; off <<= 1) {
        int t = (threadIdx.x >= off) ? s[threadIdx.x - off] : 0;
        __syncthreads();
        s[threadIdx.x] += t;
        __syncthreads();
    }
    if (i < N_NODES) {
        int rp = blockbase[blockIdx.x] + s[threadIdx.x] - v;   // exclusive
        rowptr[i] = rp;
        cursor[i] = rp;
    }
}

// per-edge score + scatter {score, src|rel<<17} (8B) into dst-sorted slots
__global__ __launch_bounds__(256) void k_edge_score(const float* __restrict__ s_src,
                                                    const float* __restrict__ s_dst,
                                                    const float* __restrict__ s_rel,
                                                    const void* __restrict__ etime,
                                                    const void* __restrict__ delta,
                                                    const int* __restrict__ src,
                                                    const int* __restrict__ dst,
                                                    const int* __restrict__ etype,
                                                    int* __restrict__ cursor,
                                                    int2* __restrict__ sorted) {
    const int bf = probe_bf(delta);
    int t = blockIdx.x * blockDim.x + threadIdx.x;
    if (t >= N_EDGES) return;
    float df = ldf(delta, 0, bf);
    int s = src[t], d = dst[t], r = etype[t];
    float sc = s_src[s] + s_dst[d] + s_rel[r];
    float e = sc > 0.f ? sc : LEAKY * sc;
    float score = (-ldf(etime, t, bf) * df) * e;
    int pos = atomicAdd(&cursor[d], 1);
    int2 rec;
    rec.x = __float_as_int(score);
    rec.y = s | (r << 17);      // src < 2^17, rel < 256
    sorted[pos] = rec;
}

// wave per node: register softmax (online over 64-edge chunks) + readlane-broadcast
// gather loop (unroll 4) + fused epilogue
__global__ __launch_bounds__(512, 6) void k_aggregate(const int* __restrict__ rowptr,
                                                      const int2* __restrict__ sorted,
                                                      const bf16* __restrict__ hWb,
                                                      const float* __restrict__ relW,
                                                      const void* __restrict__ h,
                                                      const void* __restrict__ loopW,
                                                      const void* __restrict__ evolveW,
                                                      const void* __restrict__ delta,
                                                      float* __restrict__ out) {
    const int bf = probe_bf(delta);
    __shared__ float WL[D * D];
    __shared__ float WE[D * D];
    for (int t = threadIdx.x; t < D * D; t += 512) { WL[t] = ldf(loopW, t, bf); WE[t] = ldf(evolveW, t, bf); }
    __syncthreads();
    const int wave = threadIdx.x >> 6;
    const int lane = threadIdx.x & 63;
    const int wstride = gridDim.x * 8;
    for (int i = blockIdx.x * 8 + wave; i < N_NODES; i += wstride) {
        int s0 = rowptr[i], e1 = rowptr[i + 1];
        float hv = ldf(h, (long)i * D + lane, bf);
        float acc;
        const float* W;
        if (e1 > s0) {
            float lm = -3.0e38f, ls = 0.f;
            acc = 0.f;
            for (int c = s0; c < e1; c += 64) {
                int n = e1 - c; n = n > 64 ? 64 : n;
                // cooperative coalesced record load: lane l <-> edge c+l
                float sc = -3.0e38f; int pk = 0;
                if (lane < n) {
                    int2 rec = sorted[c + lane];
                    sc = __int_as_float(rec.x);
                    pk = rec.y;
                }
                float cm = sc;
                #pragma unroll
                for (int off = 32; off; off >>= 1) cm = fmaxf(cm, __shfl_xor(cm, off));
                float newm = fmaxf(lm, cm);
                float scale = __expf(lm - newm);       // 0 on first chunk
                float ex = (lane < n) ? __expf(sc - newm) : 0.f;
                float cs = ex;
                #pragma unroll
                for (int off = 32; off; off >>= 1) cs += __shfl_xor(cs, off);
                ls = ls * scale + cs;
                acc *= scale;
                lm = newm;
                // weighted message accumulate: uniform readlane -> scalar-base gathers
                int j = 0;
                for (; j + 4 <= n; j += 4) {
                    float w0 = rl_f(ex, j),     w1 = rl_f(ex, j + 1);
                    float w2 = rl_f(ex, j + 2), w3 = rl_f(ex, j + 3);
                    int   p0 = rl_i(pk, j),     p1 = rl_i(pk, j + 1);
                    int   p2 = rl_i(pk, j + 2), p3 = rl_i(pk, j + 3);
                    float m0 = b2f(hWb[(long)(p0 & 0x1FFFF) * D + lane]) + relW[(p0 >> 17) * D + lane];
                    float m1 = b2f(hWb[(long)(p1 & 0x1FFFF) * D + lane]) + relW[(p1 >> 17) * D + lane];
                    float m2 = b2f(hWb[(long)(p2 & 0x1FFFF) * D + lane]) + relW[(p2 >> 17) * D + lane];
                    float m3 = b2f(hWb[(long)(p3 & 0x1FFFF) * D + lane]) + relW[(p3 >> 17) * D + lane];
                    acc += w0 * m0;
                    acc += w1 * m1;
                    acc += w2 * m2;
                    acc += w3 * m3;
                }
                for (; j < n; j++) {
                    float w = rl_f(ex, j);
                    int   p = rl_i(pk, j);
                    acc += w * (b2f(hWb[(long)(p & 0x1FFFF) * D + lane]) + relW[(p >> 17) * D + lane]);
                }
            }
            acc *= 1.f / ls;    // ls >= 1 (argmax edge contributes 1)
            W = WL;
        } else {
            acc = hv;
            W = WE;
        }
        // fused epilogue: acc += h[i] @ W
        #pragma unroll
        for (int k = 0; k < D; k++) {
            acc += rl_f(hv, k) * W[k * D + lane];
        }
        out[(long)i * D + lane] = acc;
    }
}

// safe diagnostic fallback
__global__ __launch_bounds__(256) void k_fallback(float* __restrict__ out) {
    int t = blockIdx.x * blockDim.x + threadIdx.x;
    if (t < N_NODES * D) out[t] = 0.f;
}

extern "C" void kernel_launch(void* const* d_in, const int* in_sizes, int n_in,
                              void* d_out, int out_size, void* d_ws, size_t ws_size,
                              hipStream_t stream) {
    const void* h       = d_in[0];
    const void* rel_emb = d_in[1];
    const void* wn      = d_in[2];
    const void* attn    = d_in[3];
    const void* delta   = d_in[4];
    const void* loopW   = d_in[5];
    const void* evolveW = d_in[6];
    const void* etime   = d_in[7];
    const int*  src     = (const int*)d_in[8];
    const int*  dst     = (const int*)d_in[9];
    const int*  etype   = (const int*)d_in[10];
    float* out = (float*)d_out;

    char* ws = (char*)d_ws;
    size_t off = 0;
    auto alloc = [&](size_t bytes) -> void* {
        off = (off + 255) & ~(size_t)255;
        void* p = ws + off;
        off += bytes;
        return p;
    };
    int2*  sorted  = (int2*) alloc((size_t)N_EDGES * 8);       // 12.8 MB
    bf16*  hWb     = (bf16*) alloc((size_t)N_NODES * D * 2);   // 12.8 MB
    float* relW    = (float*)alloc((size_t)N_RELS * D * 4);    // 51.2 KB
    float* s_src   = (float*)alloc((size_t)N_NODES * 4);       //  0.4 MB
    float* s_dst   = (float*)alloc((size_t)N_NODES * 4);       //  0.4 MB
    float* s_rel   = (float*)alloc((size_t)N_RELS * 4);        //  0.8 KB
    int*   cnt     = (int*)  alloc((size_t)N_NODES * 4);       //  0.4 MB
    int*   rowptr  = (int*)  alloc((size_t)(N_NODES + 1) * 4); //  0.4 MB
    int*   cursor  = (int*)  alloc((size_t)N_NODES * 4);       //  0.4 MB
    int*   blocksum  = (int*)alloc((size_t)NB * 4);
    int*   blockbase = (int*)alloc((size_t)NB * 4);

    if (ws_size < off) {
        k_fallback<<<(N_NODES * D + 255) / 256, 256, 0, stream>>>(out);
        return;
    }

    k_init<<<(N_NODES + 255) / 256, 256, 0, stream>>>(cnt);
    k_node_proj<<<1024, 512, 0, stream>>>(h, wn, attn, delta, hWb, s_src, s_dst);
    k_rel_proj<<<50, 256, 0, stream>>>(rel_emb, wn, attn, delta, relW, s_rel);
    k_hist<<<(N_EDGES + 255) / 256, 256, 0, stream>>>(dst, cnt);
    k_scan1<<<NB, 256, 0, stream>>>(cnt, blocksum);
    k_scan2<<<1, 256, 0, stream>>>(blocksum, blockbase, rowptr);
    k_scan3<<<NB, 256, 0, stream>>>(cnt, blockbase, rowptr, cursor);
    k_edge_score<<<(N_EDGES + 255) / 256, 256, 0, stream>>>(s_src, s_dst, s_rel, etime, delta,
                                                            src, dst, etype, cursor, sorted);
    k_aggregate<<<4096, 512, 0, stream>>>(rowptr, sorted, hWb, relW, h, loopW, evolveW, delta, out);
    (void)rel_emb;
}